// Round 1
// 121.024 us; speedup vs baseline: 1.0651x; 1.0651x over previous
//
#include <hip/hip_runtime.h>
#include <hip/hip_fp16.h>

#define NP    128   // planets per batch
#define NH    64    // hidden dim
#define ITERS 4     // batches per wave
#define WPB   4     // waves per block

typedef __attribute__((ext_vector_type(8))) _Float16 f16x8;   // K32 MFMA A/B operand
typedef __attribute__((ext_vector_type(4))) _Float16 f16x4;   // K16 MFMA A/B operand
typedef __attribute__((ext_vector_type(2))) __fp16  hf16x2;   // cvt_pkrtz return type
typedef __attribute__((ext_vector_type(4))) float f32x4;

union FragK16 { f16x4 v; unsigned int u[2]; };
union FragK32 { f16x8 v; unsigned int u[4]; };

__device__ __forceinline__ unsigned int pack_pkrtz(float a, float b) {
    hf16x2 t = __builtin_amdgcn_cvt_pkrtz(a, b);
    return __builtin_bit_cast(unsigned int, t);
}

// packed f16 relu (v_pk_max_f16). relu(rtz(x)) == rtz(relu(x)).
__device__ __forceinline__ unsigned int relu2_pk(unsigned int u) {
    hf16x2 h = __builtin_bit_cast(hf16x2, u);
    h = __builtin_elementwise_max(h, (hf16x2)(__fp16)0.f);
    return __builtin_bit_cast(unsigned int, h);
}

// 4 independent waves/block, ITERS batches each, fully register-resident, NO LDS.
//
// vs previous version: layer2 operand roles are SWAPPED (A = h-fragments,
// B = sigma-permuted W2) using the exact same register fragments — the K32
// A/B layouts are symmetric (free index on lane&15, K on (q, reg)), and the
// sigma permutation sigma(32kk+8q+j) = 16*(2kk+(j>>2)) + 4q + (j&3) applies
// identically in either role. This flips the layer2 output to msg[p][n']
// with PLANETS on the (q, reg) rows and n' on lm, so the relu'd msg tile
// (packed to fp16) is directly a 16x16x16 B-fragment and the 16-planet
// reduction becomes ONE MFMA against an all-ones A operand, accumulating
// across mi in the f32 C operand:
//     redD[np] += ones(16x16) @ msg_f16(16p x 16n')
// This moves the planet reduction from the VALU pipe (8 f32 max/add per
// np/mi) to the MFMA pipe (4 pack/relu VALU + 1 K16 MFMA) and deletes the
// entire per-batch LDS transpose-reduce (and its 2^20 bank-conflict cycles):
// after the mi loop every lane already holds out[b][16np+lm] in redD[np].
// launch_bounds (256,2): VGPR cap 256 — tighter caps caused scratch spills.
__global__ void __launch_bounds__(256, 2) gnn_wave(
    const float* __restrict__ planet_xy,  // [B][P][2]
    const float* __restrict__ planet_m,   // [P]
    const float* __restrict__ ast_xy,     // [B][2]
    const float* __restrict__ W1,         // [4][64]
    const float* __restrict__ b1,         // [64]
    const float* __restrict__ W2,         // [64][64]
    const float* __restrict__ b2,         // [64]
    float* __restrict__ out)              // [B][64]
{
    const int tid  = threadIdx.x;
    const int wv   = tid >> 6;
    const int lane = tid & 63;
    const int q    = lane >> 4;
    const int lm   = lane & 15;
    const bool q0  = (q == 0);
    const bool q1  = (q == 1);

    // ---- layer1 A-frags (16x16x16), b1 folded as constant-1 feature k=4 ----
    // A[m=16mt+lm][k=4q+j]: k<4 -> W1[k][m]; k==4 -> b1[m]; else 0.
    // Output D[h'=16mt+4q+r][p=lm]  (h on (mt,q,r), planets on lm).
    FragK16 w1f[4];
    #pragma unroll
    for (int mt = 0; mt < 4; mt++) {
        const int m = 16 * mt + lm;
        float wa = W1[0 * NH + m], wb = W1[1 * NH + m];
        float wc = W1[2 * NH + m], wd = W1[3 * NH + m];
        float be = b1[m];
        w1f[mt].u[0] = q0 ? pack_pkrtz(wa, wb) : (q1 ? pack_pkrtz(be, 0.f) : 0u);
        w1f[mt].u[1] = q0 ? pack_pkrtz(wc, wd) : 0u;
    }

    // ---- layer2 B-frags (16x16x32), sigma-permuted W2 rows ----
    // B[k=32kk+8q+j][n'=16np+lm] = W2[sigma(k)][n'],
    // sigma(32kk+8q+j) = 16*(2kk+(j>>2)) + 4q + (j&3).
    // (Same register contents as the previous version's A-frags — the K32
    //  A and B lane layouts are symmetric.)
    FragK32 w2b[4][2];   // [np][kk]
    #pragma unroll
    for (int np = 0; np < 4; np++)
        #pragma unroll
        for (int kk = 0; kk < 2; kk++) {
            const int n = 16 * np + lm;
            const int k0 = 32 * kk + 4 * q;        // j>>2 == 0 rows
            const int k1 = 32 * kk + 16 + 4 * q;   // j>>2 == 1 rows
            w2b[np][kk].u[0] = pack_pkrtz(W2[(k0 + 0) * NH + n], W2[(k0 + 1) * NH + n]);
            w2b[np][kk].u[1] = pack_pkrtz(W2[(k0 + 2) * NH + n], W2[(k0 + 3) * NH + n]);
            w2b[np][kk].u[2] = pack_pkrtz(W2[(k1 + 0) * NH + n], W2[(k1 + 1) * NH + n]);
            w2b[np][kk].u[3] = pack_pkrtz(W2[(k1 + 2) * NH + n], W2[(k1 + 3) * NH + n]);
        }

    // b2 as layer2 C-init: output rows are now PLANETS, cols are n'=16np+lm,
    // so every row gets the same b2[n'] -> broadcast into all 4 regs.
    f32x4 b2f[4];
    #pragma unroll
    for (int np = 0; np < 4; np++) {
        const float bv = b2[16 * np + lm];
        b2f[np] = (f32x4){bv, bv, bv, bv};
    }

    // batch-invariant planet masses (planet 16*i + lm)
    float pmv[8];
    #pragma unroll
    for (int i = 0; i < 8; i++)
        pmv[i] = planet_m[16 * i + lm];

    const unsigned int bf0_const = q1 ? pack_pkrtz(1.f, 0.f) : 0u;
    const f32x4 zf = (f32x4){0.f, 0.f, 0.f, 0.f};

    // all-ones A-frag for the planet-reduction MFMA: D[m][n] = sum_k B[k][n]
    FragK16 onesA;
    onesA.u[0] = 0x3C003C00u;   // (1.0h, 1.0h)
    onesA.u[1] = 0x3C003C00u;

    int b = (blockIdx.x * WPB + wv) * ITERS;

    for (int it = 0; it < ITERS; ++it, ++b) {
        const float2 axy = *(const float2*)&ast_xy[2 * b];
        float2 pxy[8];
        #pragma unroll
        for (int i = 0; i < 8; i++)
            pxy[i] = *(const float2*)&planet_xy[((size_t)b * NP + 16 * i + lm) * 2];

        // planet-reduced msg accumulators: redD[np][*] -> out[b][16np+lm]
        f32x4 redD[4];
        #pragma unroll
        for (int np = 0; np < 4; np++)
            redD[np] = zf;

        #pragma unroll
        for (int mi = 0; mi < 8; ++mi) {
            // feats B-frag for planets 16mi..16mi+15
            float dx = pxy[mi].x - axy.x, dy = pxy[mi].y - axy.y;
            float inv = __builtin_amdgcn_rsqf(fmaf(dx, dx, fmaf(dy, dy, 1e-6f)));
            FragK16 bf;
            bf.u[0] = q0 ? pack_pkrtz(dx, dy)        : bf0_const;
            bf.u[1] = q0 ? pack_pkrtz(inv, pmv[mi])  : 0u;

            // layer1: hT fragments straight into registers (K16 C layout)
            FragK16 hb[4];
            #pragma unroll
            for (int mt = 0; mt < 4; mt++) {
                f32x4 c = __builtin_amdgcn_mfma_f32_16x16x16f16(w1f[mt].v, bf.v, zf, 0, 0, 0);
                hb[mt].u[0] = relu2_pk(pack_pkrtz(c[0], c[1]));
                hb[mt].u[1] = relu2_pk(pack_pkrtz(c[2], c[3]));
            }

            // sigma-ordered K32 A-frags: pure register concatenation of hb pairs
            // A[m=p=lm][k=32kk+8q+j] = h[sigma(k)][p]
            FragK32 hA[2];
            #pragma unroll
            for (int kk = 0; kk < 2; kk++) {
                hA[kk].u[0] = hb[2 * kk + 0].u[0];
                hA[kk].u[1] = hb[2 * kk + 0].u[1];
                hA[kk].u[2] = hb[2 * kk + 1].u[0];
                hA[kk].u[3] = hb[2 * kk + 1].u[1];
            }

            // layer2 (operands SWAPPED vs prev): msg tile [p=4q+r][n'=16np+lm]
            #pragma unroll
            for (int np = 0; np < 4; np++) {
                f32x4 acc = __builtin_amdgcn_mfma_f32_16x16x32_f16(hA[0].v, w2b[np][0].v, b2f[np], 0, 0, 0);
                acc = __builtin_amdgcn_mfma_f32_16x16x32_f16(hA[1].v, w2b[np][1].v, acc, 0, 0, 0);

                // relu + pack to fp16: this IS a 16x16x16 B-frag
                // B[k=4q+j][n=lm] = relu(msg)[p=4q+j][n'=16np+lm]
                FragK16 mf;
                mf.u[0] = relu2_pk(pack_pkrtz(acc[0], acc[1]));
                mf.u[1] = relu2_pk(pack_pkrtz(acc[2], acc[3]));

                // planet reduction on the MFMA pipe: redD += ones @ mf
                // (all 4 output regs equal = running sum over planets)
                redD[np] = __builtin_amdgcn_mfma_f32_16x16x16f16(onesA.v, mf.v, redD[np], 0, 0, 0);
            }
        }

        // lane 16q+lm needs n' = lane -> select np == q; coalesced b32 store
        float v = q0 ? redD[0][0]
                : q1 ? redD[1][0]
                : (q == 2) ? redD[2][0] : redD[3][0];
        out[(size_t)b * NH + lane] = v;
    }
}

extern "C" void kernel_launch(void* const* d_in, const int* in_sizes, int n_in,
                              void* d_out, int out_size, void* d_ws, size_t ws_size,
                              hipStream_t stream) {
    const float* planet_xy = (const float*)d_in[0];
    const float* planet_m  = (const float*)d_in[1];
    const float* ast_xy    = (const float*)d_in[2];
    const float* W1        = (const float*)d_in[3];
    const float* b1        = (const float*)d_in[4];
    const float* W2        = (const float*)d_in[5];
    const float* b2        = (const float*)d_in[6];
    float* outp            = (float*)d_out;

    const int B = in_sizes[2] / 2;   // ast_xy is [B][2]
    const int batches_per_block = WPB * ITERS;
    const int grid = (B + batches_per_block - 1) / batches_per_block;

    gnn_wave<<<grid, 256, 0, stream>>>(planet_xy, planet_m, ast_xy, W1, b1, W2, b2, outp);
}